// Round 3
// baseline (1316.744 us; speedup 1.0000x reference)
//
#include <hip/hip_runtime.h>

#define N_ROWS 262144
#define DIM 64
#define KCODES 512
#define THREADS 512
#define BLK_ROWS 128                       // 8 waves x 16 rows
#define NBLOCKS (N_ROWS / BLK_ROWS)        // 2048
#define CHUNK 128                          // codes staged in LDS per pass
#define NCHUNK (KCODES / CHUNK)            // 4
#define NPART 64                           // partial histograms / sse slots (contention spread)
#define MARGIN_T 1.0e-4f                   // covers 512-ulp key quant + 3-pass bf16 err + np-fp32 dot noise

// d_out is FLOAT32. Flat layout in return order:
// [0] loss | [1 .. 1+N*D) quantized | [1+N*D] norm_perplexity | [2+N*D ..) indices
#define OFF_Q 1
#define OFF_PERP (1 + (size_t)N_ROWS * DIM)
#define OFF_IDX (2 + (size_t)N_ROWS * DIM)

typedef __attribute__((ext_vector_type(8))) short bf16x8;
typedef __attribute__((ext_vector_type(4))) float f32x4;

// ---------- numerics helpers (numpy-exact machinery, carried over) ----------

// numpy pairwise sum of squares for n=64 (loops.c.src): 8 strided accumulators,
// sequential adds, fixed combine tree. contract(off): square rounds BEFORE add.
__device__ __forceinline__ float np_sum_sq64(const float* __restrict__ v) {
#pragma clang fp contract(off)
    float r[8];
#pragma unroll
    for (int l = 0; l < 8; ++l) r[l] = v[l] * v[l];
#pragma unroll
    for (int k = 1; k < 8; ++k) {
#pragma unroll
        for (int l = 0; l < 8; ++l) {
            float sq = v[8 * k + l] * v[8 * k + l];
            r[l] = r[l] + sq;
        }
    }
    return ((r[0] + r[1]) + (r[2] + r[3])) + ((r[4] + r[5]) + (r[6] + r[7]));
}

// fp32 -> bf16 bits, round-to-nearest-even
__device__ __forceinline__ unsigned short f2bf(float f) {
    unsigned u = __float_as_uint(f);
    u += 0x7FFFu + ((u >> 16) & 1u);
    return (unsigned short)(u >> 16);
}
__device__ __forceinline__ float bf2f(unsigned short h) {
    return __uint_as_float((unsigned)h << 16);
}

// sortable-key <-> float. key = transform(t) with low 9 bits replaced by code idx.
__device__ __forceinline__ unsigned t2key(float t, unsigned idx) {
    int iu = __float_as_int(t);
    unsigned u = ((unsigned)iu) ^ (((unsigned)(iu >> 31)) | 0x80000000u);
    return (u & 0xFFFFFE00u) | idx;
}
__device__ __forceinline__ float key2t(unsigned key) {
    unsigned u = key & 0xFFFFFE00u;
    unsigned f = (u & 0x80000000u) ? (u & 0x7FFFFFFFu) : ~u;
    return __uint_as_float(f);
}

// ---------- prep: W_hi/W_lo (bf16 of -2W, split) + numpy ||w||^2 ----------

__global__ __launch_bounds__(256) void vq_prep(const float* __restrict__ W,
        unsigned short* __restrict__ WhiG, unsigned short* __restrict__ WloG,
        float* __restrict__ Bsc) {
    int c = blockIdx.x * 256 + threadIdx.x;
    if (c >= KCODES) return;
    const float* w = W + (size_t)c * DIM;
    Bsc[c] = np_sum_sq64(w);                 // numpy summation order
#pragma unroll 4
    for (int d = 0; d < DIM; ++d) {
        float v = -2.0f * w[d];              // exact scale
        unsigned short hi = f2bf(v);
        unsigned short lo = f2bf(v - bf2f(hi));   // split residual, exact subtract
        WhiG[c * DIM + d] = hi;
        WloG[c * DIM + d] = lo;
    }
}

// ---------- main: MFMA distance + packed-key min1/min2 argmin + SSE + hist ----------
// Wave w owns rows [16w,16w+16). MFMA 16x16x32_bf16: A = -2W (M=codes),
// B = X (N=rows), C-init = B_j. 3 passes: ah*xh + ah*xl + al*xh.
// D layout (m89-verified): col=lane&15 (row n), row=(lane>>4)*4+reg (code m).
// SSE_row = ||x||^2 + t1 (unflagged rows); flagged rows go to the fixup list.

__global__ __launch_bounds__(THREADS, 4) void vq_argmin(
    const float* __restrict__ X,
    const unsigned short* __restrict__ WhiG,
    const unsigned short* __restrict__ WloG,
    const float* __restrict__ Bsc,
    float* __restrict__ out,
    double* __restrict__ sseAcc,
    unsigned* __restrict__ gHistP,
    int* __restrict__ flagList,
    unsigned* __restrict__ cntArr) {

    __shared__ __align__(16) unsigned short sHi[CHUNK * DIM];  // 16 KiB, swizzled
    __shared__ __align__(16) unsigned short sLo[CHUNK * DIM];  // 16 KiB, swizzled
    __shared__ __align__(16) float sX[BLK_ROWS * DIM];         // 32 KiB, swizzled
    __shared__ __align__(16) float sB[KCODES];                 // 2 KiB
    __shared__ unsigned sHist[KCODES];                         // 2 KiB
    __shared__ int sFlagRows[BLK_ROWS];
    __shared__ unsigned sCnt;
    __shared__ double sSseW[8];

    const int tid = threadIdx.x;
    const int w = tid >> 6;          // wave 0..7
    const int l = tid & 63;          // lane
    const int q = l >> 4;            // lane quad 0..3
    const int r16 = l & 15;          // n / m sub-index
    const int R0 = blockIdx.x * BLK_ROWS;

    // ---- stage X tile (coalesced load, XOR-swizzled store: byte ^= (r&7)<<5) ----
    {
        const float4* g = (const float4*)(X + (size_t)R0 * DIM);
        char* base = (char*)sX;
#pragma unroll
        for (int i = 0; i < (BLK_ROWS * DIM / 4) / THREADS; ++i) {   // 4
            int fidx = tid + THREADS * i;                            // [0,2048)
            int r = fidx >> 4, c4 = fidx & 15;
            int off = (r * 256 + c4 * 16) ^ ((r & 7) << 5);
            *(float4*)(base + off) = g[fidx];
        }
        sB[tid] = Bsc[tid];   // THREADS == KCODES
        sHist[tid] = 0u;
        if (tid == 0) sCnt = 0u;
    }
    __syncthreads();

    // ---- per-lane X fragments: row r = 16w + (l&15), k = 32h + 8q + j ----
    // asum = lane's partial ||x||^2 over its 16 covered dims.
    bf16x8 xh[2], xl[2];
    float asum = 0.f;
    {
        const int r = w * 16 + r16;
        const char* base = (const char*)sX;
#pragma unroll
        for (int h = 0; h < 2; ++h) {
            int b0 = (r * 256 + h * 128 + q * 32) ^ ((r & 7) << 5);
            float4 fa = *(const float4*)(base + b0);
            float4 fb = *(const float4*)(base + b0 + 16);   // bit4 untouched by swizzle
            float f[8] = {fa.x, fa.y, fa.z, fa.w, fb.x, fb.y, fb.z, fb.w};
            bf16x8 hi8, lo8;
#pragma unroll
            for (int j = 0; j < 8; ++j) {
                asum = fmaf(f[j], f[j], asum);
                unsigned short hi = f2bf(f[j]);
                unsigned short lo = f2bf(f[j] - bf2f(hi));
                hi8[j] = (short)hi; lo8[j] = (short)lo;
            }
            xh[h] = hi8; xl[h] = lo8;
        }
    }

    unsigned min1 = 0xFFFFFFFFu, min2 = 0xFFFFFFFFu;

    for (int cc = 0; cc < NCHUNK; ++cc) {
        const int c0 = cc * CHUNK;
        __syncthreads();
        {   // stage -2W chunk hi+lo (coalesced uint4, swizzle: byte ^= (c&7)<<4)
            const uint4* gh = (const uint4*)(WhiG + (size_t)c0 * DIM);
            const uint4* gl = (const uint4*)(WloG + (size_t)c0 * DIM);
            char* bh = (char*)sHi; char* bl = (char*)sLo;
#pragma unroll
            for (int i = 0; i < (CHUNK * DIM / 8) / THREADS; ++i) {  // 2
                int idx = tid + THREADS * i;                          // uint4 idx
                int c = idx >> 3, k8 = idx & 7;
                int off = (c * 128 + k8 * 16) ^ ((c & 7) << 4);
                *(uint4*)(bh + off) = gh[idx];
                *(uint4*)(bl + off) = gl[idx];
            }
        }
        __syncthreads();

#pragma unroll
        for (int ct = 0; ct < CHUNK / 16; ++ct) {
            const int cloc = ct * 16 + r16;     // chunk-local code row of A frag
            const char* bh = (const char*)sHi;
            const char* bl = (const char*)sLo;
            const int sw = (cloc & 7) << 4;
            int o0 = (cloc * 128 + 16 * q) ^ sw;          // k-half 0
            int o1 = (cloc * 128 + 64 + 16 * q) ^ sw;     // k-half 1
            bf16x8 ah0 = *(const bf16x8*)(bh + o0);
            bf16x8 ah1 = *(const bf16x8*)(bh + o1);
            bf16x8 al0 = *(const bf16x8*)(bl + o0);
            bf16x8 al1 = *(const bf16x8*)(bl + o1);

            // C-init = B_j for this lane's 4 codes -> acc ends as t = B - 2*dot
            f32x4 acc = *(const f32x4*)&sB[c0 + ct * 16 + q * 4];

            acc = __builtin_amdgcn_mfma_f32_16x16x32_bf16(ah0, xh[0], acc, 0, 0, 0);
            acc = __builtin_amdgcn_mfma_f32_16x16x32_bf16(ah1, xh[1], acc, 0, 0, 0);
            acc = __builtin_amdgcn_mfma_f32_16x16x32_bf16(ah0, xl[0], acc, 0, 0, 0);
            acc = __builtin_amdgcn_mfma_f32_16x16x32_bf16(ah1, xl[1], acc, 0, 0, 0);
            acc = __builtin_amdgcn_mfma_f32_16x16x32_bf16(al0, xh[0], acc, 0, 0, 0);
            acc = __builtin_amdgcn_mfma_f32_16x16x32_bf16(al1, xh[1], acc, 0, 0, 0);

            const unsigned jbase = (unsigned)(c0 + ct * 16 + q * 4);
#pragma unroll
            for (int r = 0; r < 4; ++r) {
                unsigned key = t2key(acc[r], jbase + (unsigned)r);
                unsigned mx = min1 > key ? min1 : key;
                min2 = min2 < mx ? min2 : mx;
                min1 = min1 < key ? min1 : key;
            }
        }
    }

    // ---- merge the 4 lane-subsets of each row (lanes l, l^16, l^32, l^48) ----
    // Also merges the 4 partial ||x||^2 sums into the full per-row A.
#pragma unroll
    for (int d = 16; d <= 32; d <<= 1) {
        unsigned o1 = (unsigned)__shfl_xor((int)min1, d, 64);
        unsigned o2 = (unsigned)__shfl_xor((int)min2, d, 64);
        asum += __shfl_xor(asum, d, 64);
        unsigned n1 = min1 < o1 ? min1 : o1;
        unsigned mx = min1 > o1 ? min1 : o1;
        unsigned mn = min2 < o2 ? min2 : o2;
        unsigned n2 = mx < mn ? mx : mn;
        min1 = n1; min2 = n2;
    }

    const unsigned best = min1 & 511u;
    const float t1 = key2t(min1), t2 = key2t(min2);
    const bool flagged = (t2 < t1 + MARGIN_T);

    float ssev = 0.f;
    if (q == 0) {   // row owner: lanes 0..15 -> 16 consecutive rows, coalesced
        const int row = R0 + w * 16 + r16;
        out[OFF_IDX + row] = (float)best;    // flagged rows corrected by fixup
        if (!flagged) {
            ssev = asum + t1;                 // SSE = ||x||^2 + (B - 2*dot)
            atomicAdd(&sHist[best], 1u);
        } else {
            unsigned s = atomicAdd(&sCnt, 1u);
            sFlagRows[s] = row;
        }
    }
    // per-wave SSE reduce (owners hold nonzero), then block-level flush
#pragma unroll
    for (int off = 32; off; off >>= 1) ssev += __shfl_down(ssev, off);
    if (l == 0) sSseW[w] = (double)ssev;
    __syncthreads();

    {   // flush histogram to partial hist (spreads atomic contention 64x)
        unsigned c = sHist[tid];
        if (c) atomicAdd(&gHistP[(blockIdx.x & (NPART - 1)) * KCODES + tid], c);
    }
    if (tid < (int)sCnt) flagList[blockIdx.x * BLK_ROWS + tid] = sFlagRows[tid];
    if (tid == 0) {
        cntArr[blockIdx.x] = sCnt;
        double s = 0.0;
#pragma unroll
        for (int i = 0; i < 8; ++i) s += sSseW[i];
        atomicAdd(sseAcc, s);                 // one fp64 atomic per block (2048 total)
    }
}

// ---------- fixup: exact numpy-fp32 argmin over ALL 512 codes, listed rows ----------
// One wave per flagged row (compacted per-segment lists). Lane l owns codes
// {l, l+64, ..., l+448}: 8 exact-sequential fp64-fma dots, 4-way ILP. Wave
// u64-key shfl min-reduce, first-index tie-break. Contributes SSE (= exact e,
// NOT A+e) and histogram for its rows. No barriers.

__global__ __launch_bounds__(256) void vq_fixup(
    const float* __restrict__ X, const float* __restrict__ W,
    const float* __restrict__ Bsc, float* __restrict__ out,
    double* __restrict__ sseP, unsigned* __restrict__ gHistP,
    const int* __restrict__ flagList, const unsigned* __restrict__ cntArr) {
    const int t = threadIdx.x;
    const int wv = t >> 6, l = t & 63;
    const int seg = blockIdx.x;
    const unsigned cnt = cntArr[seg];
    if (cnt == 0) return;

    for (unsigned e = (unsigned)wv; e < cnt; e += 4) {
        const int row = flagList[seg * BLK_ROWS + (int)e];

        float xr[DIM];
        {
            const float4* Xr4 = (const float4*)(X + (size_t)row * DIM);
#pragma unroll
            for (int k4 = 0; k4 < 16; ++k4) {
                float4 v = Xr4[k4];
                xr[4 * k4 + 0] = v.x; xr[4 * k4 + 1] = v.y;
                xr[4 * k4 + 2] = v.z; xr[4 * k4 + 3] = v.w;
            }
        }
        const float A = np_sum_sq64(xr);     // numpy order, identical bits all lanes

        unsigned long long bk = ~0ULL;
#pragma unroll
        for (int g = 0; g < 2; ++g) {        // 2 groups of 4 codes, 4 indep fp64 chains
            const float4* w0 = (const float4*)(W + (size_t)(l + (4 * g + 0) * 64) * DIM);
            const float4* w1 = (const float4*)(W + (size_t)(l + (4 * g + 1) * 64) * DIM);
            const float4* w2 = (const float4*)(W + (size_t)(l + (4 * g + 2) * 64) * DIM);
            const float4* w3 = (const float4*)(W + (size_t)(l + (4 * g + 3) * 64) * DIM);
            double a0 = 0.0, a1 = 0.0, a2 = 0.0, a3 = 0.0;
#pragma unroll
            for (int k4 = 0; k4 < 16; ++k4) {
                float4 f0 = w0[k4], f1 = w1[k4], f2 = w2[k4], f3 = w3[k4];
                double x0 = (double)xr[4 * k4 + 0], x1 = (double)xr[4 * k4 + 1];
                double x2 = (double)xr[4 * k4 + 2], x3 = (double)xr[4 * k4 + 3];
                a0 = fma((double)f0.x, x0, a0); a0 = fma((double)f0.y, x1, a0);
                a0 = fma((double)f0.z, x2, a0); a0 = fma((double)f0.w, x3, a0);
                a1 = fma((double)f1.x, x0, a1); a1 = fma((double)f1.y, x1, a1);
                a1 = fma((double)f1.z, x2, a1); a1 = fma((double)f1.w, x3, a1);
                a2 = fma((double)f2.x, x0, a2); a2 = fma((double)f2.y, x1, a2);
                a2 = fma((double)f2.z, x2, a2); a2 = fma((double)f2.w, x3, a2);
                a3 = fma((double)f3.x, x0, a3); a3 = fma((double)f3.y, x1, a3);
                a3 = fma((double)f3.z, x2, a3); a3 = fma((double)f3.w, x3, a3);
            }
            double dots[4] = {a0, a1, a2, a3};
#pragma unroll
            for (int i = 0; i < 4; ++i) {
                const unsigned c = (unsigned)(l + (4 * g + i) * 64);
                float C2 = (float)(2.0 * dots[i]);
                float AB = A + Bsc[c];       // np fp32: (A+B) then subtract
                float ev = AB - C2;
                int iu = __float_as_int(ev);
                unsigned u = ((unsigned)iu) ^ (((unsigned)(iu >> 31)) | 0x80000000u);
                unsigned long long key = ((unsigned long long)u << 32) | c;
                bk = bk < key ? bk : key;    // exact e, first-index tie-break
            }
        }
#pragma unroll
        for (int d = 1; d < 64; d <<= 1) {
            unsigned long long o =
                (unsigned long long)__shfl_xor((long long)bk, d, 64);
            bk = bk < o ? bk : o;
        }
        if (l == 0) {
            unsigned bestc = (unsigned)(bk & 511ULL);
            unsigned u = (unsigned)(bk >> 32);
            unsigned fb = (u & 0x80000000u) ? (u & 0x7FFFFFFFu) : ~u;
            float ebest = __uint_as_float(fb);   // exact np-fp32 e of the winner
            out[OFF_IDX + row] = (float)bestc;
            atomicAdd(&gHistP[(seg & (NPART - 1)) * KCODES + bestc], 1u);
            atomicAdd(&sseP[seg & (NPART - 1)], (double)ebest);  // SSE = e (NOT A+e)
        }
    }
}

// ---------- scatter: pure gather W[best] -> Q (no atomics, no X read) ----------
// One wave per row. Index load is wave-uniform, W gather is one coalesced
// 256B read (L2-hot), store coalesced. Runs on FINAL indices (post-fixup).

__global__ __launch_bounds__(256) void vq_scatter(
    const float* __restrict__ W, float* __restrict__ out) {
    const int gid = blockIdx.x * 256 + threadIdx.x;
    const int row = gid >> 6;
    const int lane = gid & 63;
    int idx = (int)out[OFF_IDX + row];
    if ((unsigned)idx >= KCODES) idx = KCODES - 1;   // safety clamp
    out[OFF_Q + (size_t)row * DIM + lane] = W[(size_t)idx * DIM + lane];
}

// ---------- finalize: sum partial hists -> perplexity; sse -> loss ----------

__global__ __launch_bounds__(512) void vq_finalize(
    const double* __restrict__ sseAcc, const double* __restrict__ sseP,
    const unsigned* __restrict__ gHistP, float* __restrict__ out) {
    __shared__ float partial[8];
    const int t = threadIdx.x;
    unsigned c = 0;
#pragma unroll 8
    for (int p = 0; p < NPART; ++p) c += gHistP[p * KCODES + t];
    float pf = (float)c * (1.0f / (float)N_ROWS);
    float v = pf * logf(pf + 1e-10f);
#pragma unroll
    for (int off = 32; off; off >>= 1) v += __shfl_down(v, off);
    if ((t & 63) == 0) partial[t >> 6] = v;
    __syncthreads();
    if (t == 0) {
        float s = 0.f;
#pragma unroll
        for (int i = 0; i < 8; ++i) s += partial[i];
        out[OFF_PERP] = expf(-s) * (1.0f / (float)KCODES);
        double s2 = sseAcc[0];
#pragma unroll
        for (int i = 0; i < NPART; ++i) s2 += sseP[i];
        out[0] = (float)(1.25 * s2 * (1.0 / ((double)N_ROWS * (double)DIM)));
    }
}

extern "C" void kernel_launch(void* const* d_in, const int* in_sizes, int n_in,
                              void* d_out, int out_size, void* d_ws, size_t ws_size,
                              hipStream_t stream) {
    const float* X = (const float*)d_in[0];
    const float* W = (const float*)d_in[1];
    float* out = (float*)d_out;
    double* sseAcc = (double*)d_ws;
    double* sseP = (double*)((char*)d_ws + 64);       // 64 slots

    size_t zb = 64 + NPART * sizeof(double);          // 576 B of ws used
    if (zb > ws_size) zb = ws_size;
    hipMemsetAsync(d_ws, 0, zb, stream);

    // Scratch lives in the quantized region of `out` (dead until vq_scatter,
    // which runs LAST, overwrites it). 16B-align the base so uint4/float4
    // staging loads are aligned. Layout: WhiG | WloG | Bsc | gHistP | cnt | list.
    uintptr_t sbase = ((uintptr_t)(out + OFF_Q) + 15) & ~(uintptr_t)15;
    unsigned short* WhiG = (unsigned short*)sbase;                // 64 KiB
    unsigned short* WloG = WhiG + (size_t)KCODES * DIM;           // 64 KiB
    float* Bsc = (float*)(WloG + (size_t)KCODES * DIM);           // 2 KiB
    unsigned* gHistP = (unsigned*)(Bsc + KCODES);                 // 128 KiB
    unsigned* cntArr = gHistP + (size_t)NPART * KCODES;           // 8 KiB
    int* flagList = (int*)(cntArr + NBLOCKS);                     // 1 MiB
    hipMemsetAsync(gHistP, 0,
                   ((size_t)NPART * KCODES + NBLOCKS) * sizeof(unsigned), stream);

    vq_prep<<<2, 256, 0, stream>>>(W, WhiG, WloG, Bsc);
    vq_argmin<<<NBLOCKS, THREADS, 0, stream>>>(X, WhiG, WloG, Bsc, out,
                                               sseAcc, gHistP, flagList, cntArr);
    vq_fixup<<<NBLOCKS, 256, 0, stream>>>(X, W, Bsc, out, sseP, gHistP,
                                          flagList, cntArr);
    vq_finalize<<<1, 512, 0, stream>>>(sseAcc, sseP, gHistP, out);
    vq_scatter<<<(N_ROWS * DIM) / 256, 256, 0, stream>>>(W, out);
}

// Round 4
// 332.216 us; speedup vs baseline: 3.9635x; 3.9635x over previous
//
#include <hip/hip_runtime.h>

#define N_ROWS 262144
#define DIM 64
#define KCODES 512
#define THREADS 512
#define BLK_ROWS 128                       // 8 waves x 16 rows
#define NBLOCKS (N_ROWS / BLK_ROWS)        // 2048
#define CHUNK 128                          // codes staged in LDS per pass
#define NCHUNK (KCODES / CHUNK)            // 4
#define NPART 64                           // partial histograms / sse slots (contention spread)
#define MARGIN_T 1.0e-4f                   // covers 512-ulp key quant + 3-pass bf16 err + np-fp32 dot noise

// d_out is FLOAT32. Flat layout in return order:
// [0] loss | [1 .. 1+N*D) quantized | [1+N*D] norm_perplexity | [2+N*D ..) indices
#define OFF_Q 1
#define OFF_PERP (1 + (size_t)N_ROWS * DIM)
#define OFF_IDX (2 + (size_t)N_ROWS * DIM)

typedef __attribute__((ext_vector_type(8))) short bf16x8;
typedef __attribute__((ext_vector_type(4))) float f32x4;

// ---------- numerics helpers (numpy-exact machinery, carried over) ----------

// numpy pairwise sum of squares for n=64 (loops.c.src): 8 strided accumulators,
// sequential adds, fixed combine tree. contract(off): square rounds BEFORE add.
__device__ __forceinline__ float np_sum_sq64(const float* __restrict__ v) {
#pragma clang fp contract(off)
    float r[8];
#pragma unroll
    for (int l = 0; l < 8; ++l) r[l] = v[l] * v[l];
#pragma unroll
    for (int k = 1; k < 8; ++k) {
#pragma unroll
        for (int l = 0; l < 8; ++l) {
            float sq = v[8 * k + l] * v[8 * k + l];
            r[l] = r[l] + sq;
        }
    }
    return ((r[0] + r[1]) + (r[2] + r[3])) + ((r[4] + r[5]) + (r[6] + r[7]));
}

// fp32 -> bf16 bits, round-to-nearest-even
__device__ __forceinline__ unsigned short f2bf(float f) {
    unsigned u = __float_as_uint(f);
    u += 0x7FFFu + ((u >> 16) & 1u);
    return (unsigned short)(u >> 16);
}
__device__ __forceinline__ float bf2f(unsigned short h) {
    return __uint_as_float((unsigned)h << 16);
}

// sortable-key <-> float. key = transform(t) with low 9 bits replaced by code idx.
__device__ __forceinline__ unsigned t2key(float t, unsigned idx) {
    int iu = __float_as_int(t);
    unsigned u = ((unsigned)iu) ^ (((unsigned)(iu >> 31)) | 0x80000000u);
    return (u & 0xFFFFFE00u) | idx;
}
__device__ __forceinline__ float key2t(unsigned key) {
    unsigned u = key & 0xFFFFFE00u;
    unsigned f = (u & 0x80000000u) ? (u & 0x7FFFFFFFu) : ~u;
    return __uint_as_float(f);
}

// ---------- prep: W_hi/W_lo (bf16 of -2W, split) + numpy ||w||^2 ----------

__global__ __launch_bounds__(256) void vq_prep(const float* __restrict__ W,
        unsigned short* __restrict__ WhiG, unsigned short* __restrict__ WloG,
        float* __restrict__ Bsc) {
    int c = blockIdx.x * 256 + threadIdx.x;
    if (c >= KCODES) return;
    const float* w = W + (size_t)c * DIM;
    Bsc[c] = np_sum_sq64(w);                 // numpy summation order
#pragma unroll 4
    for (int d = 0; d < DIM; ++d) {
        float v = -2.0f * w[d];              // exact scale
        unsigned short hi = f2bf(v);
        unsigned short lo = f2bf(v - bf2f(hi));   // split residual, exact subtract
        WhiG[c * DIM + d] = hi;
        WloG[c * DIM + d] = lo;
    }
}

// ---------- main: MFMA distance + packed-key min1/min2 argmin + SSE + hist ----------
// Wave w owns rows [16w,16w+16). MFMA 16x16x32_bf16: A = -2W (M=codes),
// B = X (N=rows), C-init = B_j. 3 passes: ah*xh + ah*xl + al*xh.
// D layout (m89-verified): col=lane&15 (row n), row=(lane>>4)*4+reg (code m).
// SSE_row = ||x||^2 + t1 (unflagged rows); flagged rows go to the fixup list.

__global__ __launch_bounds__(THREADS, 4) void vq_argmin(
    const float* __restrict__ X,
    const unsigned short* __restrict__ WhiG,
    const unsigned short* __restrict__ WloG,
    const float* __restrict__ Bsc,
    float* __restrict__ out,
    double* __restrict__ sseAcc,
    unsigned* __restrict__ gHistP,
    int* __restrict__ flagList,
    unsigned* __restrict__ cntArr) {

    __shared__ __align__(16) unsigned short sHi[CHUNK * DIM];  // 16 KiB, swizzled
    __shared__ __align__(16) unsigned short sLo[CHUNK * DIM];  // 16 KiB, swizzled
    __shared__ __align__(16) float sX[BLK_ROWS * DIM];         // 32 KiB, swizzled
    __shared__ __align__(16) float sB[KCODES];                 // 2 KiB
    __shared__ unsigned sHist[KCODES];                         // 2 KiB
    __shared__ int sFlagRows[BLK_ROWS];
    __shared__ unsigned sCnt;
    __shared__ double sSseW[8];

    const int tid = threadIdx.x;
    const int w = tid >> 6;          // wave 0..7
    const int l = tid & 63;          // lane
    const int q = l >> 4;            // lane quad 0..3
    const int r16 = l & 15;          // n / m sub-index
    const int R0 = blockIdx.x * BLK_ROWS;

    // ---- stage X tile (coalesced load, XOR-swizzled store: byte ^= (r&7)<<5) ----
    {
        const float4* g = (const float4*)(X + (size_t)R0 * DIM);
        char* base = (char*)sX;
#pragma unroll
        for (int i = 0; i < (BLK_ROWS * DIM / 4) / THREADS; ++i) {   // 4
            int fidx = tid + THREADS * i;                            // [0,2048)
            int r = fidx >> 4, c4 = fidx & 15;
            int off = (r * 256 + c4 * 16) ^ ((r & 7) << 5);
            *(float4*)(base + off) = g[fidx];
        }
        sB[tid] = Bsc[tid];   // THREADS == KCODES
        sHist[tid] = 0u;
        if (tid == 0) sCnt = 0u;
    }
    __syncthreads();

    // ---- per-lane X fragments: row r = 16w + (l&15), k = 32h + 8q + j ----
    // asum = lane's partial ||x||^2 over its 16 covered dims.
    bf16x8 xh[2], xl[2];
    float asum = 0.f;
    {
        const int r = w * 16 + r16;
        const char* base = (const char*)sX;
#pragma unroll
        for (int h = 0; h < 2; ++h) {
            int b0 = (r * 256 + h * 128 + q * 32) ^ ((r & 7) << 5);
            float4 fa = *(const float4*)(base + b0);
            float4 fb = *(const float4*)(base + b0 + 16);   // bit4 untouched by swizzle
            float f[8] = {fa.x, fa.y, fa.z, fa.w, fb.x, fb.y, fb.z, fb.w};
            bf16x8 hi8, lo8;
#pragma unroll
            for (int j = 0; j < 8; ++j) {
                asum = fmaf(f[j], f[j], asum);
                unsigned short hi = f2bf(f[j]);
                unsigned short lo = f2bf(f[j] - bf2f(hi));
                hi8[j] = (short)hi; lo8[j] = (short)lo;
            }
            xh[h] = hi8; xl[h] = lo8;
        }
    }

    unsigned min1 = 0xFFFFFFFFu, min2 = 0xFFFFFFFFu;

    for (int cc = 0; cc < NCHUNK; ++cc) {
        const int c0 = cc * CHUNK;
        __syncthreads();
        {   // stage -2W chunk hi+lo (coalesced uint4, swizzle: byte ^= (c&7)<<4)
            const uint4* gh = (const uint4*)(WhiG + (size_t)c0 * DIM);
            const uint4* gl = (const uint4*)(WloG + (size_t)c0 * DIM);
            char* bh = (char*)sHi; char* bl = (char*)sLo;
#pragma unroll
            for (int i = 0; i < (CHUNK * DIM / 8) / THREADS; ++i) {  // 2
                int idx = tid + THREADS * i;                          // uint4 idx
                int c = idx >> 3, k8 = idx & 7;
                int off = (c * 128 + k8 * 16) ^ ((c & 7) << 4);
                *(uint4*)(bh + off) = gh[idx];
                *(uint4*)(bl + off) = gl[idx];
            }
        }
        __syncthreads();

#pragma unroll
        for (int ct = 0; ct < CHUNK / 16; ++ct) {
            const int cloc = ct * 16 + r16;     // chunk-local code row of A frag
            const char* bh = (const char*)sHi;
            const char* bl = (const char*)sLo;
            const int sw = (cloc & 7) << 4;
            int o0 = (cloc * 128 + 16 * q) ^ sw;          // k-half 0
            int o1 = (cloc * 128 + 64 + 16 * q) ^ sw;     // k-half 1
            bf16x8 ah0 = *(const bf16x8*)(bh + o0);
            bf16x8 ah1 = *(const bf16x8*)(bh + o1);
            bf16x8 al0 = *(const bf16x8*)(bl + o0);
            bf16x8 al1 = *(const bf16x8*)(bl + o1);

            // C-init = B_j for this lane's 4 codes -> acc ends as t = B - 2*dot
            f32x4 acc = *(const f32x4*)&sB[c0 + ct * 16 + q * 4];

            acc = __builtin_amdgcn_mfma_f32_16x16x32_bf16(ah0, xh[0], acc, 0, 0, 0);
            acc = __builtin_amdgcn_mfma_f32_16x16x32_bf16(ah1, xh[1], acc, 0, 0, 0);
            acc = __builtin_amdgcn_mfma_f32_16x16x32_bf16(ah0, xl[0], acc, 0, 0, 0);
            acc = __builtin_amdgcn_mfma_f32_16x16x32_bf16(ah1, xl[1], acc, 0, 0, 0);
            acc = __builtin_amdgcn_mfma_f32_16x16x32_bf16(al0, xh[0], acc, 0, 0, 0);
            acc = __builtin_amdgcn_mfma_f32_16x16x32_bf16(al1, xh[1], acc, 0, 0, 0);

            const unsigned jbase = (unsigned)(c0 + ct * 16 + q * 4);
#pragma unroll
            for (int r = 0; r < 4; ++r) {
                unsigned key = t2key(acc[r], jbase + (unsigned)r);
                unsigned mx = min1 > key ? min1 : key;
                min2 = min2 < mx ? min2 : mx;
                min1 = min1 < key ? min1 : key;
            }
        }
    }

    // ---- merge the 4 lane-subsets of each row (lanes l, l^16, l^32, l^48) ----
    // Also merges the 4 partial ||x||^2 sums into the full per-row A.
#pragma unroll
    for (int d = 16; d <= 32; d <<= 1) {
        unsigned o1 = (unsigned)__shfl_xor((int)min1, d, 64);
        unsigned o2 = (unsigned)__shfl_xor((int)min2, d, 64);
        asum += __shfl_xor(asum, d, 64);
        unsigned n1 = min1 < o1 ? min1 : o1;
        unsigned mx = min1 > o1 ? min1 : o1;
        unsigned mn = min2 < o2 ? min2 : o2;
        unsigned n2 = mx < mn ? mx : mn;
        min1 = n1; min2 = n2;
    }

    const unsigned best = min1 & 511u;
    const float t1 = key2t(min1), t2 = key2t(min2);
    const bool flagged = (t2 < t1 + MARGIN_T);

    float ssev = 0.f;
    if (q == 0) {   // row owner: lanes 0..15 -> 16 consecutive rows, coalesced
        const int row = R0 + w * 16 + r16;
        out[OFF_IDX + row] = (float)best;    // flagged rows corrected by fixup
        if (!flagged) {
            ssev = asum + t1;                 // SSE = ||x||^2 + (B - 2*dot)
            atomicAdd(&sHist[best], 1u);
        } else {
            unsigned s = atomicAdd(&sCnt, 1u);
            sFlagRows[s] = row;
        }
    }
    // per-wave SSE reduce (owners hold nonzero), then block-level flush
#pragma unroll
    for (int off = 32; off; off >>= 1) ssev += __shfl_down(ssev, off);
    if (l == 0) sSseW[w] = (double)ssev;
    __syncthreads();

    {   // flush histogram to partial hist (spreads atomic contention 64x)
        unsigned c = sHist[tid];
        if (c) atomicAdd(&gHistP[(blockIdx.x & (NPART - 1)) * KCODES + tid], c);
    }
    if (tid < (int)sCnt) flagList[blockIdx.x * BLK_ROWS + tid] = sFlagRows[tid];
    if (tid == 0) {
        cntArr[blockIdx.x] = sCnt;
        double s = 0.0;
#pragma unroll
        for (int i = 0; i < 8; ++i) s += sSseW[i];
        atomicAdd(sseAcc, s);                 // one fp64 atomic per block (2048 total)
    }
}

// ---------- fixup: exact numpy-fp32 argmin over ALL 512 codes, listed rows ----------
// One wave per flagged row (compacted per-segment lists). The X row lives in
// PER-WAVE LDS and is read through a volatile pointer -> the compiler cannot
// rebuild a 64-float register copy (round-3 spill bug: VGPR=256, 1.18 GB
// scratch traffic). Lane l owns codes {l, l+64, ..., l+448}: 8 exact-sequential
// fp64-fma dots (bit-identical order to np_e), 2-way ILP. Wave u64-key shfl
// min-reduce, first-index tie-break. Contributes SSE (= exact e) + histogram.
// No __syncthreads: each wave owns its own LDS buffer and its own rows.

__global__ __launch_bounds__(256) void vq_fixup(
    const float* __restrict__ X, const float* __restrict__ W,
    const float* __restrict__ Bsc, float* __restrict__ out,
    double* __restrict__ sseP, unsigned* __restrict__ gHistP,
    const int* __restrict__ flagList, const unsigned* __restrict__ cntArr) {
    __shared__ float sx[4][DIM];             // per-wave X row (1 KiB)
    const int t = threadIdx.x;
    const int wv = t >> 6, l = t & 63;
    const int seg = blockIdx.x;
    const unsigned cnt = cntArr[seg];
    if (cnt == 0) return;

    for (unsigned e = (unsigned)wv; e < cnt; e += 4) {   // wave-uniform loop
        const int row = flagList[seg * BLK_ROWS + (int)e];
        sx[wv][l] = X[(size_t)row * DIM + l];            // coalesced 256B
        asm volatile("s_waitcnt lgkmcnt(0)" ::: "memory");
        __builtin_amdgcn_sched_barrier(0);               // rule #18 fence
        const volatile float* xp = sx[wv];               // broadcast reads, no CSE

        // A: numpy pairwise order, streamed from LDS (no register x-array)
        float A;
        {
#pragma clang fp contract(off)
            float r[8];
#pragma unroll
            for (int i = 0; i < 8; ++i) { float v = xp[i]; r[i] = v * v; }
#pragma unroll
            for (int k = 1; k < 8; ++k) {
#pragma unroll
                for (int i = 0; i < 8; ++i) {
                    float v = xp[8 * k + i];
                    float sq = v * v;
                    r[i] = r[i] + sq;
                }
            }
            A = ((r[0] + r[1]) + (r[2] + r[3])) + ((r[4] + r[5]) + (r[6] + r[7]));
        }

        unsigned long long bk = ~0ULL;
#pragma unroll
        for (int g = 0; g < 4; ++g) {        // 2 codes per group, 2 indep fp64 chains
            const unsigned c0 = (unsigned)(l + (2 * g + 0) * 64);
            const unsigned c1 = (unsigned)(l + (2 * g + 1) * 64);
            const float4* w0 = (const float4*)(W + (size_t)c0 * DIM);
            const float4* w1 = (const float4*)(W + (size_t)c1 * DIM);
            double a0 = 0.0, a1 = 0.0;
#pragma unroll
            for (int k4 = 0; k4 < 16; ++k4) {
                float4 f0 = w0[k4], f1 = w1[k4];
                double x0 = (double)xp[4 * k4 + 0], x1 = (double)xp[4 * k4 + 1];
                double x2 = (double)xp[4 * k4 + 2], x3 = (double)xp[4 * k4 + 3];
                a0 = fma((double)f0.x, x0, a0); a0 = fma((double)f0.y, x1, a0);
                a0 = fma((double)f0.z, x2, a0); a0 = fma((double)f0.w, x3, a0);
                a1 = fma((double)f1.x, x0, a1); a1 = fma((double)f1.y, x1, a1);
                a1 = fma((double)f1.z, x2, a1); a1 = fma((double)f1.w, x3, a1);
            }
#pragma unroll
            for (int i = 0; i < 2; ++i) {
                const unsigned c = i ? c1 : c0;
                const double dot = i ? a1 : a0;
                float C2 = (float)(2.0 * dot);
                float AB = A + Bsc[c];       // np fp32: (A+B) then subtract
                float ev = AB - C2;
                int iu = __float_as_int(ev);
                unsigned u = ((unsigned)iu) ^ (((unsigned)(iu >> 31)) | 0x80000000u);
                unsigned long long key = ((unsigned long long)u << 32) | c;
                bk = bk < key ? bk : key;    // exact e, first-index tie-break
            }
        }
#pragma unroll
        for (int d = 1; d < 64; d <<= 1) {
            unsigned long long o =
                (unsigned long long)__shfl_xor((long long)bk, d, 64);
            bk = bk < o ? bk : o;
        }
        if (l == 0) {
            unsigned bestc = (unsigned)(bk & 511ULL);
            unsigned u = (unsigned)(bk >> 32);
            unsigned fb = (u & 0x80000000u) ? (u & 0x7FFFFFFFu) : ~u;
            float ebest = __uint_as_float(fb);   // exact np-fp32 e of the winner
            out[OFF_IDX + row] = (float)bestc;
            atomicAdd(&gHistP[(seg & (NPART - 1)) * KCODES + bestc], 1u);
            atomicAdd(&sseP[seg & (NPART - 1)], (double)ebest);  // SSE = e (NOT A+e)
        }
    }
}

// ---------- scatter: pure gather W[best] -> Q (no atomics, no X read) ----------
// One wave per row. Index load is wave-uniform, W gather is one coalesced
// 256B read (L2-hot), store coalesced. Runs on FINAL indices (post-fixup).

__global__ __launch_bounds__(256) void vq_scatter(
    const float* __restrict__ W, float* __restrict__ out) {
    const int gid = blockIdx.x * 256 + threadIdx.x;
    const int row = gid >> 6;
    const int lane = gid & 63;
    int idx = (int)out[OFF_IDX + row];
    if ((unsigned)idx >= KCODES) idx = KCODES - 1;   // safety clamp
    out[OFF_Q + (size_t)row * DIM + lane] = W[(size_t)idx * DIM + lane];
}

// ---------- finalize: sum partial hists -> perplexity; sse -> loss ----------

__global__ __launch_bounds__(512) void vq_finalize(
    const double* __restrict__ sseAcc, const double* __restrict__ sseP,
    const unsigned* __restrict__ gHistP, float* __restrict__ out) {
    __shared__ float partial[8];
    const int t = threadIdx.x;
    unsigned c = 0;
#pragma unroll 8
    for (int p = 0; p < NPART; ++p) c += gHistP[p * KCODES + t];
    float pf = (float)c * (1.0f / (float)N_ROWS);
    float v = pf * logf(pf + 1e-10f);
#pragma unroll
    for (int off = 32; off; off >>= 1) v += __shfl_down(v, off);
    if ((t & 63) == 0) partial[t >> 6] = v;
    __syncthreads();
    if (t == 0) {
        float s = 0.f;
#pragma unroll
        for (int i = 0; i < 8; ++i) s += partial[i];
        out[OFF_PERP] = expf(-s) * (1.0f / (float)KCODES);
        double s2 = sseAcc[0];
#pragma unroll
        for (int i = 0; i < NPART; ++i) s2 += sseP[i];
        out[0] = (float)(1.25 * s2 * (1.0 / ((double)N_ROWS * (double)DIM)));
    }
}

extern "C" void kernel_launch(void* const* d_in, const int* in_sizes, int n_in,
                              void* d_out, int out_size, void* d_ws, size_t ws_size,
                              hipStream_t stream) {
    const float* X = (const float*)d_in[0];
    const float* W = (const float*)d_in[1];
    float* out = (float*)d_out;
    double* sseAcc = (double*)d_ws;
    double* sseP = (double*)((char*)d_ws + 64);       // 64 slots

    size_t zb = 64 + NPART * sizeof(double);          // 576 B of ws used
    if (zb > ws_size) zb = ws_size;
    hipMemsetAsync(d_ws, 0, zb, stream);

    // Scratch lives in the quantized region of `out` (dead until vq_scatter,
    // which runs LAST, overwrites it). 16B-align the base so uint4/float4
    // staging loads are aligned. Layout: WhiG | WloG | Bsc | gHistP | cnt | list.
    uintptr_t sbase = ((uintptr_t)(out + OFF_Q) + 15) & ~(uintptr_t)15;
    unsigned short* WhiG = (unsigned short*)sbase;                // 64 KiB
    unsigned short* WloG = WhiG + (size_t)KCODES * DIM;           // 64 KiB
    float* Bsc = (float*)(WloG + (size_t)KCODES * DIM);           // 2 KiB
    unsigned* gHistP = (unsigned*)(Bsc + KCODES);                 // 128 KiB
    unsigned* cntArr = gHistP + (size_t)NPART * KCODES;           // 8 KiB
    int* flagList = (int*)(cntArr + NBLOCKS);                     // 1 MiB
    hipMemsetAsync(gHistP, 0,
                   ((size_t)NPART * KCODES + NBLOCKS) * sizeof(unsigned), stream);

    vq_prep<<<2, 256, 0, stream>>>(W, WhiG, WloG, Bsc);
    vq_argmin<<<NBLOCKS, THREADS, 0, stream>>>(X, WhiG, WloG, Bsc, out,
                                               sseAcc, gHistP, flagList, cntArr);
    vq_fixup<<<NBLOCKS, 256, 0, stream>>>(X, W, Bsc, out, sseP, gHistP,
                                          flagList, cntArr);
    vq_finalize<<<1, 512, 0, stream>>>(sseAcc, sseP, gHistP, out);
    vq_scatter<<<(N_ROWS * DIM) / 256, 256, 0, stream>>>(W, out);
}